// Round 12
// baseline (109.596 us; speedup 1.0000x reference)
//
#include <hip/hip_runtime.h>

#define NTOT  16384
#define NFEAT 300
#define NHID  512
#define NOUT  256
#define NACT  64
#define NEIGH 2048
#define SSZ   2112   // NACT + NEIGH
#define CSTR  64     // cols row stride (shorts); first 8 sentinel-padded
#define GEMMT 528    // 66 x 8 tiles of 32x64
#define K1BLK (GEMMT + SSZ + 8 + 1)   // 2649
#define K2BLK 528    // 4 waves/block, one wave per row

union SM1 {
    struct {
        int scur[2304];
        unsigned int bm[512];
        unsigned long long smask[9][4];
        int spre[40];
    } scan;
    struct { float As[16][36]; float Bs[16][64]; } gemm;
};

// ===== K1: gemm || stream-scan || u=W2@iw || nb-out + B1 zero + ticket=0 ====
__global__ __launch_bounds__(256) void k_front(
        const float* __restrict__ adj, const int* __restrict__ act,
        const int* __restrict__ nb,  const float* __restrict__ x,
        const float* __restrict__ W1, const float* __restrict__ W2,
        const float* __restrict__ iw,
        int* __restrict__ cnt, unsigned short* __restrict__ cols,
        float* __restrict__ B1, float* __restrict__ u,
        float* __restrict__ out, int* __restrict__ ticket)
{
    __shared__ SM1 sm;
    const int t = threadIdx.x;
    const int w = t >> 6, lane = t & 63;
    const int bid = blockIdx.x;

    if (bid < GEMMT) {
        // ---------------- GEMM tile 32x64 of X[cur] @ W1 --------------------
        int bm_ = (bid % 66) * 32, bn = (bid / 66) * 64;
        int tx = t & 15, ty = t >> 4;
        float acc[2][4] = {};
        for (int kt = 0; kt < NFEAT; kt += 16) {
#pragma unroll
            for (int l = 0; l < 2; ++l) {
                int idx = t + l * 256;
                int m = idx >> 4, kk = idx & 15;
                int gk = kt + kk, gm = bm_ + m;
                int ar = (gm < NACT) ? act[gm] : nb[gm - NACT];
                sm.gemm.As[kk][m] = (gk < NFEAT) ? x[(size_t)ar * NFEAT + gk] : 0.0f;
            }
#pragma unroll
            for (int l = 0; l < 4; ++l) {
                int idx = t + l * 256;
                int nn = idx & 63, kk = idx >> 6;
                int gk = kt + kk;
                sm.gemm.Bs[kk][nn] = (gk < NFEAT) ? W1[(size_t)gk * NHID + bn + nn] : 0.0f;
            }
            __syncthreads();
#pragma unroll
            for (int kk = 0; kk < 16; ++kk) {
                float a0 = sm.gemm.As[kk][ty * 2], a1 = sm.gemm.As[kk][ty * 2 + 1];
                float4 bv = *(const float4*)&sm.gemm.Bs[kk][tx * 4];
                acc[0][0] += a0 * bv.x; acc[0][1] += a0 * bv.y;
                acc[0][2] += a0 * bv.z; acc[0][3] += a0 * bv.w;
                acc[1][0] += a1 * bv.x; acc[1][1] += a1 * bv.y;
                acc[1][2] += a1 * bv.z; acc[1][3] += a1 * bv.w;
            }
            __syncthreads();
        }
#pragma unroll
        for (int r = 0; r < 2; ++r) {
            int gm = bm_ + ty * 2 + r;
            *(float4*)&B1[(size_t)gm * NHID + bn + tx * 4] =
                make_float4(acc[r][0], acc[r][1], acc[r][2], acc[r][3]);
        }
    } else if (bid < GEMMT + SSZ) {
        // ---- stream-scan: full-row read + LDS bitmap + ballot compaction ----
        const int row = bid - GEMMT;
        int rowid = (row < NACT) ? act[row] : nb[row - NACT];
        const float4* rowv = (const float4*)(adj + (size_t)rowid * NTOT);

        float4 vv[16];
#pragma unroll
        for (int k = 0; k < 16; ++k) vv[k] = rowv[t + (k << 8)];

        for (int k = t; k < 2304; k += 256)
            sm.scan.scur[k] = (k < NACT) ? act[k] : (k < SSZ ? nb[k - NACT] : 0);
        for (int k = t; k < 512; k += 256) sm.scan.bm[k] = 0;
        __syncthreads();

#pragma unroll
        for (int k = 0; k < 16; ++k) {
            int cb = (t + (k << 8)) << 2;
            unsigned int m = 0;
            if (vv[k].x != 0.0f) m |= 1u << ((cb + 0) & 31);
            if (vv[k].y != 0.0f) m |= 1u << ((cb + 1) & 31);
            if (vv[k].z != 0.0f) m |= 1u << ((cb + 2) & 31);
            if (vv[k].w != 0.0f) m |= 1u << ((cb + 3) & 31);
            if (m) atomicOr(&sm.scan.bm[cb >> 5], m);
        }
        __syncthreads();

        bool hit[9];
#pragma unroll
        for (int k = 0; k < 9; ++k) {
            int j = t + (k << 8);
            int c = sm.scan.scur[j];
            hit[k] = (j < SSZ) && ((sm.scan.bm[c >> 5] >> (c & 31)) & 1u);
            unsigned long long m = __ballot(hit[k]);
            if (lane == 0) sm.scan.smask[k][w] = m;
        }
        __syncthreads();
        if (t < 64) {
            int c = (t < 36) ? __popcll(sm.scan.smask[t >> 2][t & 3]) : 0;
            int vvp = c;
#pragma unroll
            for (int o = 1; o < 64; o <<= 1) {
                int xx = __shfl_up(vvp, o, 64);
                if (lane >= o) vvp += xx;
            }
            if (t == 0) sm.scan.spre[0] = 0;
            if (t < 36) sm.scan.spre[t + 1] = vvp;
        }
        __syncthreads();
        unsigned short* dst = cols + (size_t)row * CSTR;
#pragma unroll
        for (int k = 0; k < 9; ++k) {
            if (hit[k]) {
                unsigned long long below = sm.scan.smask[k][w] & ((1ull << lane) - 1ull);
                dst[sm.scan.spre[k * 4 + w] + __popcll(below)] =
                    (unsigned short)(t + (k << 8));
            }
        }
        int n = sm.scan.spre[36];
        if (t == 0) cnt[row] = n;
        if (t >= n && t < 8) dst[t] = (unsigned short)SSZ;   // sentinel pad
    } else if (bid < GEMMT + SSZ + 8) {
        // ---------------- u = W2 @ imp_w, 64 rows per block ------------------
        int r0 = (bid - GEMMT - SSZ) * 64;
        for (int r = r0 + w; r < r0 + 64; r += 4) {
            float p = 0.0f;
#pragma unroll
            for (int q = 0; q < 4; ++q)
                p += W2[(size_t)r * NOUT + lane + q * 64] * iw[lane + q * 64];
#pragma unroll
            for (int o = 32; o > 0; o >>= 1) p += __shfl_down(p, o, 64);
            if (lane == 0) u[r] = p;
        }
    } else {
        // ------- nb -> out tail; zero B1 sentinel row; reset ticket ----------
        for (int i = t; i < NEIGH; i += 256) out[NEIGH + i] = (float)nb[i];
        B1[(size_t)SSZ * NHID + t] = 0.0f;
        B1[(size_t)SSZ * NHID + t + 256] = 0.0f;
        if (t == 0) *ticket = 0;
    }
}

// extract 8 padded column indices from one 16B cols load
#define CL8(c4, cl)                                                  \
    int cl[8];                                                       \
    cl[0] = (c4).x & 0xFFFF; cl[1] = (c4).x >> 16;                   \
    cl[2] = (c4).y & 0xFFFF; cl[3] = (c4).y >> 16;                   \
    cl[4] = (c4).z & 0xFFFF; cl[5] = (c4).z >> 16;                   \
    cl[6] = (c4).w & 0xFFFF; cl[7] = (c4).w >> 16;

union SM2 {
    float su[NHID];
    struct { float sv[SSZ + 1]; float s1[SSZ + 1]; float s2[SSZ]; } fin;
};

// ===== K2+K3: wave-per-row relu-spMV, last block runs the final =============
__global__ __launch_bounds__(256) void k_back(
        const float* __restrict__ B1, const int* __restrict__ cnt,
        const unsigned short* __restrict__ cols, const float* __restrict__ u,
        const float* __restrict__ ib, float* __restrict__ v,
        int* __restrict__ ticket, float* __restrict__ out)
{
    __shared__ SM2 sm;
    __shared__ float wsum[4];
    __shared__ float sinv;
    __shared__ int lastFlag;
    const int t = threadIdx.x;
    const int w = t >> 6, lane = t & 63;

    sm.su[t] = u[t];
    sm.su[t + 256] = u[t + 256];
    __syncthreads();

    // ---- spMV: one wave per row, branchless-8 gather -----------------------
    const int row = blockIdx.x * 4 + w;           // 528*4 == 2112
    uint4 c4 = *(const uint4*)(cols + (size_t)row * CSTR);
    CL8(c4, cl)
    int n = cnt[row];

    float a[8] = {};
#pragma unroll
    for (int k = 0; k < 8; ++k) {
        const float* br = B1 + (size_t)cl[k] * NHID;
#pragma unroll
        for (int q = 0; q < 8; ++q) a[q] += br[lane + q * 64];
    }
    if (n > 8) {                                   // rare high-degree fallback
        const unsigned short* cp = cols + (size_t)row * CSTR;
        for (int k = 8; k < n; ++k) {
            const float* br = B1 + (size_t)cp[k] * NHID;
#pragma unroll
            for (int q = 0; q < 8; ++q) a[q] += br[lane + q * 64];
        }
    }
    float p = 0.0f;
#pragma unroll
    for (int q = 0; q < 8; ++q) p += fmaxf(a[q], 0.0f) * sm.su[lane + q * 64];
#pragma unroll
    for (int o = 32; o > 0; o >>= 1) p += __shfl_down(p, o, 64);
    if (lane == 0)
        __hip_atomic_store(&v[row], p, __ATOMIC_RELAXED, __HIP_MEMORY_SCOPE_AGENT);

    // ---- ticket (no fences: barrier drains vmcnt; stores are agent-atomic) --
    __syncthreads();
    if (t == 0) {
        int old = __hip_atomic_fetch_add(ticket, 1, __ATOMIC_ACQ_REL,
                                         __HIP_MEMORY_SCOPE_AGENT);
        lastFlag = (old == K2BLK - 1);
    }
    __syncthreads();
    if (!lastFlag) return;

    // ---- final on the last block: s1 = A@v, s2 = A@s1 + b, L1 norm ---------
    for (int i = t; i < SSZ; i += 256)
        sm.fin.sv[i] = __hip_atomic_load(&v[i], __ATOMIC_RELAXED,
                                         __HIP_MEMORY_SCOPE_AGENT);
    if (t == 0) { sm.fin.sv[SSZ] = 0.0f; sm.fin.s1[SSZ] = 0.0f; }
    __syncthreads();

    for (int i = t; i < SSZ; i += 256) {           // pass 1
        uint4 c = *(const uint4*)(cols + (size_t)i * CSTR);
        CL8(c, ci)
        float s = 0.0f;
#pragma unroll
        for (int k = 0; k < 8; ++k) s += sm.fin.sv[ci[k]];
        int ni = cnt[i];
        if (ni > 8) { const unsigned short* cp = cols + (size_t)i * CSTR;
                      for (int k = 8; k < ni; ++k) s += sm.fin.sv[cp[k]]; }
        sm.fin.s1[i] = s;
    }
    __syncthreads();
    float bias = ib[0];
    for (int i = t; i < SSZ; i += 256) {           // pass 2
        uint4 c = *(const uint4*)(cols + (size_t)i * CSTR);
        CL8(c, ci)
        float s = 0.0f;
#pragma unroll
        for (int k = 0; k < 8; ++k) s += sm.fin.s1[ci[k]];
        int ni = cnt[i];
        if (ni > 8) { const unsigned short* cp = cols + (size_t)i * CSTR;
                      for (int k = 8; k < ni; ++k) s += sm.fin.s1[cp[k]]; }
        sm.fin.s2[i] = s + bias;
    }
    __syncthreads();
    float s = 0.0f;
    for (int i = t; i < SSZ; i += 256) s += fabsf(sm.fin.s2[i]);
#pragma unroll
    for (int o = 32; o > 0; o >>= 1) s += __shfl_down(s, o, 64);
    if ((t & 63) == 0) wsum[t >> 6] = s;
    __syncthreads();
    if (t == 0) sinv = 1.0f / fmaxf(wsum[0] + wsum[1] + wsum[2] + wsum[3], 1e-12f);
    __syncthreads();
    for (int i = t; i < NEIGH; i += 256) out[i] = sm.fin.s2[NACT + i] * sinv;
}

// --------------------------------------------------------------------------
extern "C" void kernel_launch(void* const* d_in, const int* in_sizes, int n_in,
                              void* d_out, int out_size, void* d_ws, size_t ws_size,
                              hipStream_t stream) {
    const float* x   = (const float*)d_in[0];
    const float* adj = (const float*)d_in[1];
    const int*   act = (const int*)d_in[2];
    const int*   nb  = (const int*)d_in[3];
    const float* W1  = (const float*)d_in[4];
    const float* W2  = (const float*)d_in[5];
    const float* iw  = (const float*)d_in[6];
    const float* ib  = (const float*)d_in[7];
    float* out = (float*)d_out;

    // workspace layout (bytes) — total ~4.62 MB; B1 has +1 zero sentinel row
    char* ws = (char*)d_ws;
    int*            cnt    = (int*)           (ws + 0);        // 8448 B
    unsigned short* cols   = (unsigned short*)(ws + 8704);     // 270336 B
    float*          B1     = (float*)         (ws + 279040);   // 2113 x 2KB
    float*          u      = (float*)         (ws + 4606464);  // 2 KB
    float*          v      = (float*)         (ws + 4608512);  // 8448 B
    int*            ticket = (int*)           (ws + 4616960);  // 4 B

    k_front<<<dim3(K1BLK), 256, 0, stream>>>(adj, act, nb, x, W1, W2, iw,
                                             cnt, cols, B1, u, out, ticket);
    k_back <<<dim3(K2BLK), 256, 0, stream>>>(B1, cnt, cols, u, ib, v,
                                             ticket, out);
}

// Round 13
// 88.292 us; speedup vs baseline: 1.2413x; 1.2413x over previous
//
#include <hip/hip_runtime.h>

#define NTOT  16384
#define NFEAT 300
#define NHID  512
#define NOUT  256
#define NACT  64
#define NEIGH 2048
#define SSZ   2112   // NACT + NEIGH
#define CSTR  64     // cols row stride (shorts); first 8 padded with SSZ sentinel
#define GEMMT 528    // 66 x 8 tiles of 32x64
#define K1BLK (GEMMT + SSZ + 8 + 1)   // 2649

union SM1 {
    struct {
        int scur[2304];
        unsigned int bm[512];
        unsigned long long smask[9][4];
        int spre[40];
    } scan;
    struct { float As[16][36]; float Bs[16][64]; } gemm;
};

// ===== K1: gemm || stream-scan || u=W2@iw || nb-out + B1 zero-row ===========
__global__ __launch_bounds__(256) void k_front(
        const float* __restrict__ adj, const int* __restrict__ act,
        const int* __restrict__ nb,  const float* __restrict__ x,
        const float* __restrict__ W1, const float* __restrict__ W2,
        const float* __restrict__ iw,
        int* __restrict__ cnt, unsigned short* __restrict__ cols,
        float* __restrict__ B1, float* __restrict__ u,
        float* __restrict__ out)
{
    __shared__ SM1 sm;
    const int t = threadIdx.x;
    const int w = t >> 6, lane = t & 63;
    const int bid = blockIdx.x;

    if (bid < GEMMT) {
        // ---------------- GEMM tile 32x64 of X[cur] @ W1 --------------------
        int bm_ = (bid % 66) * 32, bn = (bid / 66) * 64;
        int tx = t & 15, ty = t >> 4;
        float acc[2][4] = {};
        for (int kt = 0; kt < NFEAT; kt += 16) {
#pragma unroll
            for (int l = 0; l < 2; ++l) {
                int idx = t + l * 256;
                int m = idx >> 4, kk = idx & 15;
                int gk = kt + kk, gm = bm_ + m;
                int ar = (gm < NACT) ? act[gm] : nb[gm - NACT];
                sm.gemm.As[kk][m] = (gk < NFEAT) ? x[(size_t)ar * NFEAT + gk] : 0.0f;
            }
#pragma unroll
            for (int l = 0; l < 4; ++l) {
                int idx = t + l * 256;
                int nn = idx & 63, kk = idx >> 6;
                int gk = kt + kk;
                sm.gemm.Bs[kk][nn] = (gk < NFEAT) ? W1[(size_t)gk * NHID + bn + nn] : 0.0f;
            }
            __syncthreads();
#pragma unroll
            for (int kk = 0; kk < 16; ++kk) {
                float a0 = sm.gemm.As[kk][ty * 2], a1 = sm.gemm.As[kk][ty * 2 + 1];
                float4 bv = *(const float4*)&sm.gemm.Bs[kk][tx * 4];
                acc[0][0] += a0 * bv.x; acc[0][1] += a0 * bv.y;
                acc[0][2] += a0 * bv.z; acc[0][3] += a0 * bv.w;
                acc[1][0] += a1 * bv.x; acc[1][1] += a1 * bv.y;
                acc[1][2] += a1 * bv.z; acc[1][3] += a1 * bv.w;
            }
            __syncthreads();
        }
#pragma unroll
        for (int r = 0; r < 2; ++r) {
            int gm = bm_ + ty * 2 + r;
            *(float4*)&B1[(size_t)gm * NHID + bn + tx * 4] =
                make_float4(acc[r][0], acc[r][1], acc[r][2], acc[r][3]);
        }
    } else if (bid < GEMMT + SSZ) {
        // ---- stream-scan: full-row read + LDS bitmap + ballot compaction ----
        const int row = bid - GEMMT;
        int rowid = (row < NACT) ? act[row] : nb[row - NACT];
        const float4* rowv = (const float4*)(adj + (size_t)rowid * NTOT);

        float4 vv[16];
#pragma unroll
        for (int k = 0; k < 16; ++k) vv[k] = rowv[t + (k << 8)];

        for (int k = t; k < 2304; k += 256)
            sm.scan.scur[k] = (k < NACT) ? act[k] : (k < SSZ ? nb[k - NACT] : 0);
        for (int k = t; k < 512; k += 256) sm.scan.bm[k] = 0;
        __syncthreads();

#pragma unroll
        for (int k = 0; k < 16; ++k) {
            int cb = (t + (k << 8)) << 2;
            unsigned int m = 0;
            if (vv[k].x != 0.0f) m |= 1u << ((cb + 0) & 31);
            if (vv[k].y != 0.0f) m |= 1u << ((cb + 1) & 31);
            if (vv[k].z != 0.0f) m |= 1u << ((cb + 2) & 31);
            if (vv[k].w != 0.0f) m |= 1u << ((cb + 3) & 31);
            if (m) atomicOr(&sm.scan.bm[cb >> 5], m);
        }
        __syncthreads();

        bool hit[9];
#pragma unroll
        for (int k = 0; k < 9; ++k) {
            int j = t + (k << 8);
            int c = sm.scan.scur[j];
            hit[k] = (j < SSZ) && ((sm.scan.bm[c >> 5] >> (c & 31)) & 1u);
            unsigned long long m = __ballot(hit[k]);
            if (lane == 0) sm.scan.smask[k][w] = m;
        }
        __syncthreads();
        if (t < 64) {
            int c = (t < 36) ? __popcll(sm.scan.smask[t >> 2][t & 3]) : 0;
            int vvp = c;
#pragma unroll
            for (int o = 1; o < 64; o <<= 1) {
                int xx = __shfl_up(vvp, o, 64);
                if (lane >= o) vvp += xx;
            }
            if (t == 0) sm.scan.spre[0] = 0;
            if (t < 36) sm.scan.spre[t + 1] = vvp;
        }
        __syncthreads();
        unsigned short* dst = cols + (size_t)row * CSTR;
#pragma unroll
        for (int k = 0; k < 9; ++k) {
            if (hit[k]) {
                unsigned long long below = sm.scan.smask[k][w] & ((1ull << lane) - 1ull);
                dst[sm.scan.spre[k * 4 + w] + __popcll(below)] =
                    (unsigned short)(t + (k << 8));
            }
        }
        int n = sm.scan.spre[36];
        if (t == 0) cnt[row] = n;
        if (t >= n && t < 8) dst[t] = (unsigned short)SSZ;   // zero-row sentinel pad
    } else if (bid < GEMMT + SSZ + 8) {
        // ---------------- u = W2 @ imp_w, 64 rows per block ------------------
        int r0 = (bid - GEMMT - SSZ) * 64;
        for (int r = r0 + w; r < r0 + 64; r += 4) {
            float p = 0.0f;
#pragma unroll
            for (int q = 0; q < 4; ++q)
                p += W2[(size_t)r * NOUT + lane + q * 64] * iw[lane + q * 64];
#pragma unroll
            for (int o = 32; o > 0; o >>= 1) p += __shfl_down(p, o, 64);
            if (lane == 0) u[r] = p;
        }
    } else {
        // ---------------- nb -> out tail; zero B1 sentinel row ---------------
        for (int i = t; i < NEIGH; i += 256) out[NEIGH + i] = (float)nb[i];
        B1[(size_t)SSZ * NHID + t] = 0.0f;
        B1[(size_t)SSZ * NHID + t + 256] = 0.0f;
    }
}

// extract 8 padded column indices from one 16B cols load
#define CL8(c4, cl)                                                  \
    int cl[8];                                                       \
    cl[0] = (c4).x & 0xFFFF; cl[1] = (c4).x >> 16;                   \
    cl[2] = (c4).y & 0xFFFF; cl[3] = (c4).y >> 16;                   \
    cl[4] = (c4).z & 0xFFFF; cl[5] = (c4).z >> 16;                   \
    cl[6] = (c4).w & 0xFFFF; cl[7] = (c4).w >> 16;

// ===== K2: relu-spMV, one block per row, branchless-8 gather ================
__global__ __launch_bounds__(256) void k_spmv(const float* __restrict__ B1,
                                              const int* __restrict__ cnt,
                                              const unsigned short* __restrict__ cols,
                                              const float* __restrict__ u,
                                              float* __restrict__ v) {
    __shared__ float su[NHID];
    __shared__ float wsum[4];
    int t = threadIdx.x, row = blockIdx.x;
    su[t] = u[t]; su[t + 256] = u[t + 256];

    uint4 c4 = *(const uint4*)(cols + (size_t)row * CSTR);
    CL8(c4, cl)
    int n = cnt[row];

    float a0 = 0.0f, a1 = 0.0f;
#pragma unroll
    for (int k = 0; k < 8; ++k) {                 // 16 independent loads
        const float* br = B1 + (size_t)cl[k] * NHID;
        a0 += br[t];
        a1 += br[t + 256];
    }
    if (n > 8) {                                  // rare high-degree fallback
        const unsigned short* cp = cols + (size_t)row * CSTR;
        for (int k = 8; k < n; ++k) {
            const float* br = B1 + (size_t)cp[k] * NHID;
            a0 += br[t];
            a1 += br[t + 256];
        }
    }
    __syncthreads();
    float p = fmaxf(a0, 0.0f) * su[t] + fmaxf(a1, 0.0f) * su[t + 256];
#pragma unroll
    for (int o = 32; o > 0; o >>= 1) p += __shfl_down(p, o, 64);
    if ((t & 63) == 0) wsum[t >> 6] = p;
    __syncthreads();
    if (t == 0) v[row] = wsum[0] + wsum[1] + wsum[2] + wsum[3];
}

// ===== K3: final, single block x 1024, branchless-8 both passes =============
__global__ __launch_bounds__(1024) void k_final(const int* __restrict__ cnt,
                                                const unsigned short* __restrict__ cols,
                                                const float* __restrict__ v,
                                                const float* __restrict__ ib,
                                                float* __restrict__ out) {
    __shared__ float sv[SSZ + 1];
    __shared__ float s1[SSZ + 1];
    __shared__ float s2[SSZ];
    __shared__ float wsum[16];
    __shared__ float inv;
    int t = threadIdx.x;

    // rows owned by this thread: t, t+1024, t+2048(t<64)
    uint4 c40 = *(const uint4*)(cols + (size_t)t * CSTR);
    uint4 c41 = *(const uint4*)(cols + (size_t)(t + 1024) * CSTR);
    uint4 c42 = (t < 64) ? *(const uint4*)(cols + (size_t)(t + 2048) * CSTR)
                         : make_uint4(0, 0, 0, 0);
    int n0 = cnt[t], n1 = cnt[t + 1024], n2 = (t < 64) ? cnt[t + 2048] : 0;
    CL8(c40, cA)
    CL8(c41, cB)
    CL8(c42, cC)

    for (int i = t; i < SSZ; i += 1024) sv[i] = v[i];
    if (t == 0) { sv[SSZ] = 0.0f; s1[SSZ] = 0.0f; }
    __syncthreads();

    // ---- pass 1: s1 = A @ v -------------------------------------------------
    {
        float s = 0.0f;
#pragma unroll
        for (int k = 0; k < 8; ++k) s += sv[cA[k]];
        if (n0 > 8) { const unsigned short* cp = cols + (size_t)t * CSTR;
                      for (int k = 8; k < n0; ++k) s += sv[cp[k]]; }
        s1[t] = s;
        s = 0.0f;
#pragma unroll
        for (int k = 0; k < 8; ++k) s += sv[cB[k]];
        if (n1 > 8) { const unsigned short* cp = cols + (size_t)(t + 1024) * CSTR;
                      for (int k = 8; k < n1; ++k) s += sv[cp[k]]; }
        s1[t + 1024] = s;
        if (t < 64) {
            s = 0.0f;
#pragma unroll
            for (int k = 0; k < 8; ++k) s += sv[cC[k]];
            if (n2 > 8) { const unsigned short* cp = cols + (size_t)(t + 2048) * CSTR;
                          for (int k = 8; k < n2; ++k) s += sv[cp[k]]; }
            s1[t + 2048] = s;
        }
    }
    __syncthreads();

    // ---- pass 2: s2 = A @ s1 + b --------------------------------------------
    float bias = ib[0];
    {
        float s = 0.0f;
#pragma unroll
        for (int k = 0; k < 8; ++k) s += s1[cA[k]];
        if (n0 > 8) { const unsigned short* cp = cols + (size_t)t * CSTR;
                      for (int k = 8; k < n0; ++k) s += s1[cp[k]]; }
        s2[t] = s + bias;
        s = 0.0f;
#pragma unroll
        for (int k = 0; k < 8; ++k) s += s1[cB[k]];
        if (n1 > 8) { const unsigned short* cp = cols + (size_t)(t + 1024) * CSTR;
                      for (int k = 8; k < n1; ++k) s += s1[cp[k]]; }
        s2[t + 1024] = s + bias;
        if (t < 64) {
            s = 0.0f;
#pragma unroll
            for (int k = 0; k < 8; ++k) s += s1[cC[k]];
            if (n2 > 8) { const unsigned short* cp = cols + (size_t)(t + 2048) * CSTR;
                          for (int k = 8; k < n2; ++k) s += s1[cp[k]]; }
            s2[t + 2048] = s + bias;
        }
    }
    __syncthreads();

    // ---- L1 norm + output ----------------------------------------------------
    float s = 0.0f;
    for (int i = t; i < SSZ; i += 1024) s += fabsf(s2[i]);
#pragma unroll
    for (int o = 32; o > 0; o >>= 1) s += __shfl_down(s, o, 64);
    if ((t & 63) == 0) wsum[t >> 6] = s;
    __syncthreads();
    if (t == 0) {
        float tot = 0.0f;
#pragma unroll
        for (int k = 0; k < 16; ++k) tot += wsum[k];
        inv = 1.0f / fmaxf(tot, 1e-12f);
    }
    __syncthreads();
    for (int i = t; i < NEIGH; i += 1024) out[i] = s2[NACT + i] * inv;
}

// --------------------------------------------------------------------------
extern "C" void kernel_launch(void* const* d_in, const int* in_sizes, int n_in,
                              void* d_out, int out_size, void* d_ws, size_t ws_size,
                              hipStream_t stream) {
    const float* x   = (const float*)d_in[0];
    const float* adj = (const float*)d_in[1];
    const int*   act = (const int*)d_in[2];
    const int*   nb  = (const int*)d_in[3];
    const float* W1  = (const float*)d_in[4];
    const float* W2  = (const float*)d_in[5];
    const float* iw  = (const float*)d_in[6];
    const float* ib  = (const float*)d_in[7];
    float* out = (float*)d_out;

    // workspace layout (bytes) — total ~4.62 MB; B1 has +1 zero sentinel row
    char* ws = (char*)d_ws;
    int*            cnt  = (int*)           (ws + 0);        // 8448 B
    unsigned short* cols = (unsigned short*)(ws + 8704);     // 270336 B
    float*          B1   = (float*)         (ws + 279040);   // 2113 rows x 2KB
    float*          u    = (float*)         (ws + 4606464);  // 2 KB
    float*          v    = (float*)         (ws + 4608512);  // 8448 B

    k_front<<<dim3(K1BLK), 256,  0, stream>>>(adj, act, nb, x, W1, W2, iw,
                                              cnt, cols, B1, u, out);
    k_spmv <<<dim3(SSZ),   256,  0, stream>>>(B1, cnt, cols, u, v);
    k_final<<<dim3(1),     1024, 0, stream>>>(cnt, cols, v, ib, out);
}